// Round 1
// baseline (120.794 us; speedup 1.0000x reference)
//
#include <hip/hip_runtime.h>
#include <cmath>

// Problem constants (fixed by the reference's init kwargs):
//   POS_FREQS=31, W_MIN=0.1, W_MAX=1.0, PATCH=16 -> grid H=64 (row 63 padded), W=32
//   batch_triangles: [64,128,3,2] f32, lengths: [64] i32
//   outputs: mag [64,1,64,32] f32 then phase [64,1,64,32] f32, concatenated flat.
#define BB     64
#define MAXN   128
#define HH     64
#define WW     32
#define NFREQ  (HH*WW)      // 2048
#define BLK    256
#define BLOCKS_PER_B (NFREQ/BLK)  // 8

__global__ __launch_bounds__(BLK) void poly_cft_kernel(
    const float* __restrict__ tris,    // [64,128,3,2]
    const int*   __restrict__ lengths, // [64]
    float*       __restrict__ out)     // [2*64*2048]
{
    // Per-triangle staged data (broadcast-read in the main loop):
    __shared__ float4 sA[MAXN];  // xq, yq, e1x=xr-xq, e1y=yr-yq
    __shared__ float4 sB[MAXN];  // e2x=xs-xr, e2y=ys-yr, area, unused
    __shared__ float  s_posw[31];

    const int b = blockIdx.x >> 3;                       // 8 blocks per batch elem
    const int p = ((blockIdx.x & 7) << 8) | threadIdx.x; // 0..2047 freq point
    const int h = p >> 5;
    const int w = p & 31;

    const int N = lengths[b];

    // Frequency grid values, matching numpy:
    //   g = (1.0/0.1)**(1/30) computed in double (1.0/0.1 == 10.0 exactly in f64)
    //   pos_w[k] = float32(0.1 * g**k)
    if (threadIdx.x < 31) {
        double g = pow(10.0, 1.0 / 30.0);
        s_posw[threadIdx.x] = (float)(0.1 * pow(g, (double)threadIdx.x));
    }

    // Stage all 128 triangles of this batch element (N <= 127 always, but
    // loading all avoids a dependence on N here).
    if (threadIdx.x < MAXN) {
        const float* t = tris + ((size_t)b * MAXN + threadIdx.x) * 6;
        float xq = t[0], yq = t[1];
        float xr = t[2], yr = t[3];
        float xs = t[4], ys = t[5];
        float det  = xq * (yr - ys) + xr * (ys - yq) + xs * (yq - yr);
        float area = fabsf(0.5f * det);
        sA[threadIdx.x] = make_float4(xq, yq, xr - xq, yr - yq);
        sB[threadIdx.x] = make_float4(xs - xr, ys - yr, area, 0.0f);
    }
    __syncthreads();

    // U = Wx[h], V = Wy[w]
    float U;
    if (h < 31)       U = -s_posw[30 - h];
    else if (h == 31) U = 0.0f;
    else if (h < 63)  U = s_posw[h - 32];
    else              U = 0.0f;   // padded row (masked out at the end)
    const float V = (w == 0) ? 0.0f : s_posw[w - 1];

    // float32 constants exactly as the reference builds them:
    const float PI_F     = 3.14159274101257324f;        // np.float32(np.pi)
    const float TWOPI    = 6.28318548202514648f;        // 2*pi_f (exact doubling)
    const float FOUR_PI2 = (4.0f * PI_F) * PI_F;        // np.float32(4)*pi*pi, same assoc

    float accR = 0.0f, accI = 0.0f;

    for (int n = 0; n < N; ++n) {
        const float4 A  = sA[n];
        const float4 Bv = sB[n];
        const float xq = A.x,  yq = A.y,  e1x = A.z, e1y = A.w;
        const float e2x = Bv.x, e2y = Bv.y, area = Bv.z;

        // Mask-determining quantities: MUST be plain mul/mul/add (no FMA
        // contraction) to reproduce the reference's exact-zero pattern.
        const float U_ = __fadd_rn(__fmul_rn(U, e1x), __fmul_rn(V, e1y));
        const float V_ = __fadd_rn(__fmul_rn(U, e2x), __fmul_rn(V, e2y));
        const float S  = __fadd_rn(U_, V_);

        const bool uz = (U_ == 0.0f);
        const bool vz = (V_ == 0.0f);

        if (uz && vz) {
            // zero_mask: FT = area (real), no phase factor
            accR += area;
        } else {
            float su, cu, sv, cv, sp, cp;
            sincosf(TWOPI * U_, &su, &cu);
            sincosf(TWOPI * V_, &sv, &cv);
            const float t = U * xq + V * yq;
            sincosf(TWOPI * t, &sp, &cp);

            float p1, p2r, p2i;
            if (S == 0.0f) {
                // diag: part1 = -1/(4pi^2 U_^2); part2 = e^{-2pi i U_} + 2pi i U_ - 1
                p1  = -1.0f / (FOUR_PI2 * U_ * U_);
                p2r = cu - 1.0f;
                p2i = TWOPI * U_ - su;
            } else if (uz) {
                // u_mask: part1 = -1/(4pi^2 V_^2); part2 = e^{-2pi i V_} + 2pi i V_ - 1
                p1  = -1.0f / (FOUR_PI2 * V_ * V_);
                p2r = cv - 1.0f;
                p2i = TWOPI * V_ - sv;
            } else if (vz) {
                // v_mask: part1 = 1/(4pi^2 U_^2); part2 = (2pi i U_ + 1) e^{-2pi i U_} - 1
                p1  = 1.0f / (FOUR_PI2 * U_ * U_);
                p2r = cu + TWOPI * U_ * su - 1.0f;
                p2i = TWOPI * U_ * cu - su;
            } else {
                // normal: part1 = 1/(4pi^2 U_ V_ (U_+V_))
                //         part2 = -U_ e^{-2pi i (U_+V_)} + (U_+V_) e^{-2pi i U_} - V_
                const float cuv = cu * cv - su * sv;   // cos(2pi(U_+V_))
                const float suv = su * cv + cu * sv;   // sin(2pi(U_+V_))
                p1  = 1.0f / (FOUR_PI2 * U_ * V_ * S);
                p2r = -U_ * cuv + S * cu - V_;
                p2i =  U_ * suv - S * su;
            }

            // FT = 2*area*part1 * part2 * e^{-2pi i t}; psi = cp - i sp
            const float k   = 2.0f * area * p1;
            const float ftr = k * (p2r * cp + p2i * sp);
            const float fti = k * (p2i * cp - p2r * sp);
            accR += ftr;
            accI += fti;
        }
    }

    // pad mask: row 63 is padding
    if (h == 63) { accR = 0.0f; accI = 0.0f; }

    // mag = log1p(|FT|) with exact-zero handling; phase = atan2(im, re) with
    // re replaced by 1 when m2 == 0 (matches angle(0) = 0).
    const float m2 = __fadd_rn(__fmul_rn(accR, accR), __fmul_rn(accI, accI));
    float mag, ph;
    if (m2 == 0.0f) {
        mag = 0.0f;
        ph  = atan2f(accI, 1.0f);
    } else {
        mag = log1pf(sqrtf(m2));
        ph  = atan2f(accI, accR);
    }

    const int o = b * NFREQ + p;
    out[o]                 = mag;  // mag block: [64,1,64,32]
    out[BB * NFREQ + o]    = ph;   // phase block follows
}

extern "C" void kernel_launch(void* const* d_in, const int* in_sizes, int n_in,
                              void* d_out, int out_size, void* d_ws, size_t ws_size,
                              hipStream_t stream) {
    const float* tris    = (const float*)d_in[0]; // [64,128,3,2] f32
    const int*   lengths = (const int*)d_in[1];   // [64] i32
    float*       out     = (float*)d_out;         // [2*64*2048] f32

    poly_cft_kernel<<<dim3(BB * BLOCKS_PER_B), dim3(BLK), 0, stream>>>(tris, lengths, out);
}

// Round 2
// 101.912 us; speedup vs baseline: 1.1853x; 1.1853x over previous
//
#include <hip/hip_runtime.h>
#include <cmath>

// Problem constants (fixed by the reference's init kwargs):
//   POS_FREQS=31, W_MIN=0.1, W_MAX=1.0, PATCH=16 -> grid H=64 (row 63 padded), W=32
//   batch_triangles: [64,128,3,2] f32, lengths: [64] i32
//   outputs: mag [64,1,64,32] f32 then phase [64,1,64,32] f32, concatenated flat.
#define BB     64
#define MAXN   128
#define HH     64
#define WW     32
#define NFREQ  (HH*WW)      // 2048
#define BLK    256
#define PCHUNKS (NFREQ/BLK) // 8 point-chunks per batch elem
#define TRI_CHUNK 32
#define QQ     (MAXN/TRI_CHUNK) // 4 triangle chunks
// workspace: float2 partial[QQ][BB][NFREQ] = 4*64*2048*8 B = 4 MB

__global__ __launch_bounds__(BLK) void poly_cft_partial(
    const float* __restrict__ tris,    // [64,128,3,2]
    const int*   __restrict__ lengths, // [64]
    float2*      __restrict__ ws)      // [QQ][BB][NFREQ] partial sums
{
    __shared__ float4 sA[TRI_CHUNK];  // xq, yq, e1x=xr-xq, e1y=yr-yq
    __shared__ float4 sB[TRI_CHUNK];  // e2x=xs-xr, e2y=ys-yr, area, unused
    __shared__ float  s_posw[31];

    const int pc = blockIdx.x;                 // 0..7 point chunk
    const int q  = blockIdx.y;                 // 0..3 triangle chunk
    const int b  = blockIdx.z;                 // 0..63 batch elem
    const int p  = (pc << 8) | threadIdx.x;    // 0..2047 freq point
    const int h  = p >> 5;
    const int w  = p & 31;

    const int N   = lengths[b];
    const int n0  = q * TRI_CHUNK;
    const int cnt = min(n0 + TRI_CHUNK, N) - n0;   // may be <= 0

    // Frequency grid values, matching numpy exactly:
    //   g = (1.0/0.1)**(1/30) in double; pos_w[k] = float32(0.1 * g**k)
    if (threadIdx.x < 31) {
        double g = pow(10.0, 1.0 / 30.0);
        s_posw[threadIdx.x] = (float)(0.1 * pow(g, (double)threadIdx.x));
    }

    if ((int)threadIdx.x < cnt) {
        const float* t = tris + ((size_t)b * MAXN + n0 + threadIdx.x) * 6;
        float xq = t[0], yq = t[1];
        float xr = t[2], yr = t[3];
        float xs = t[4], ys = t[5];
        float det  = xq * (yr - ys) + xr * (ys - yq) + xs * (yq - yr);
        float area = fabsf(0.5f * det);
        sA[threadIdx.x] = make_float4(xq, yq, xr - xq, yr - yq);
        sB[threadIdx.x] = make_float4(xs - xr, ys - yr, area, 0.0f);
    }
    __syncthreads();

    // U = Wx[h], V = Wy[w]
    float U;
    if (h < 31)       U = -s_posw[30 - h];
    else if (h == 31) U = 0.0f;
    else if (h < 63)  U = s_posw[h - 32];
    else              U = 0.0f;   // padded row (masked in finalize)
    const float V = (w == 0) ? 0.0f : s_posw[w - 1];

    // float32 constants exactly as the reference builds them:
    const float PI_F     = 3.14159274101257324f;   // np.float32(np.pi)
    const float TWOPI    = 6.28318548202514648f;   // 2*pi_f
    const float FOUR_PI2 = (4.0f * PI_F) * PI_F;   // np.float32(4)*pi*pi

    float accR = 0.0f, accI = 0.0f;

    for (int n = 0; n < cnt; ++n) {
        const float4 A  = sA[n];
        const float4 Bv = sB[n];
        const float xq = A.x,  yq = A.y,  e1x = A.z, e1y = A.w;
        const float e2x = Bv.x, e2y = Bv.y, area = Bv.z;

        // Mask-determining quantities: plain mul/mul/add (no FMA contraction)
        // to reproduce the reference's exact-zero pattern.
        const float U_ = __fadd_rn(__fmul_rn(U, e1x), __fmul_rn(V, e1y));
        const float V_ = __fadd_rn(__fmul_rn(U, e2x), __fmul_rn(V, e2y));
        const float S  = __fadd_rn(U_, V_);

        const bool uz = (U_ == 0.0f);
        const bool vz = (V_ == 0.0f);

        if (uz && vz) {
            accR += area;          // zero_mask: FT = area (real)
        } else {
            float su, cu, sv, cv, sp, cp;
            sincosf(TWOPI * U_, &su, &cu);
            sincosf(TWOPI * V_, &sv, &cv);
            const float t = U * xq + V * yq;
            sincosf(TWOPI * t, &sp, &cp);

            float p1, p2r, p2i;
            if (S == 0.0f) {
                p1  = -1.0f / (FOUR_PI2 * U_ * U_);
                p2r = cu - 1.0f;
                p2i = TWOPI * U_ - su;
            } else if (uz) {
                p1  = -1.0f / (FOUR_PI2 * V_ * V_);
                p2r = cv - 1.0f;
                p2i = TWOPI * V_ - sv;
            } else if (vz) {
                p1  = 1.0f / (FOUR_PI2 * U_ * U_);
                p2r = cu + TWOPI * U_ * su - 1.0f;
                p2i = TWOPI * U_ * cu - su;
            } else {
                const float cuv = cu * cv - su * sv;   // cos(2pi(U_+V_))
                const float suv = su * cv + cu * sv;   // sin(2pi(U_+V_))
                p1  = 1.0f / (FOUR_PI2 * U_ * V_ * S);
                p2r = -U_ * cuv + S * cu - V_;
                p2i =  U_ * suv - S * su;
            }

            const float k   = 2.0f * area * p1;
            accR += k * (p2r * cp + p2i * sp);
            accI += k * (p2i * cp - p2r * sp);
        }
    }

    ws[((size_t)q * BB + b) * NFREQ + p] = make_float2(accR, accI);
}

__global__ __launch_bounds__(BLK) void poly_cft_finalize(
    const float2* __restrict__ ws,   // [QQ][BB][NFREQ]
    float*        __restrict__ out)  // [2*64*2048]
{
    const int idx = blockIdx.x * BLK + threadIdx.x;  // 0..131071
    const int b = idx >> 11;
    const int p = idx & (NFREQ - 1);
    const int h = p >> 5;

    float accR = 0.0f, accI = 0.0f;
#pragma unroll
    for (int q = 0; q < QQ; ++q) {
        float2 v = ws[((size_t)q * BB + b) * NFREQ + p];
        accR += v.x;
        accI += v.y;
    }

    if (h == 63) { accR = 0.0f; accI = 0.0f; }   // pad row

    const float m2 = __fadd_rn(__fmul_rn(accR, accR), __fmul_rn(accI, accI));
    float mag, ph;
    if (m2 == 0.0f) {
        mag = 0.0f;
        ph  = atan2f(accI, 1.0f);   // angle(0) = 0 semantics
    } else {
        mag = log1pf(sqrtf(m2));
        ph  = atan2f(accI, accR);
    }

    out[idx]              = mag;   // mag block [64,1,64,32]
    out[BB * NFREQ + idx] = ph;    // phase block follows
}

extern "C" void kernel_launch(void* const* d_in, const int* in_sizes, int n_in,
                              void* d_out, int out_size, void* d_ws, size_t ws_size,
                              hipStream_t stream) {
    const float* tris    = (const float*)d_in[0]; // [64,128,3,2] f32
    const int*   lengths = (const int*)d_in[1];   // [64] i32
    float*       out     = (float*)d_out;         // [2*64*2048] f32
    float2*      partial = (float2*)d_ws;         // 4 MB of scratch

    poly_cft_partial<<<dim3(PCHUNKS, QQ, BB), dim3(BLK), 0, stream>>>(tris, lengths, partial);
    poly_cft_finalize<<<dim3(BB * NFREQ / BLK), dim3(BLK), 0, stream>>>(partial, out);
}

// Round 3
// 83.573 us; speedup vs baseline: 1.4454x; 1.2194x over previous
//
#include <hip/hip_runtime.h>
#include <cmath>

// Problem constants (fixed by the reference's init kwargs):
//   POS_FREQS=31, W_MIN=0.1, W_MAX=1.0, PATCH=16 -> grid H=64 (row 63 padded), W=32
//   batch_triangles: [64,128,3,2] f32, lengths: [64] i32
//   outputs: mag [64,1,64,32] f32 then phase [64,1,64,32] f32, concatenated flat.
#define BB     64
#define MAXN   128
#define HH     64
#define WW     32
#define NFREQ  (HH*WW)      // 2048
#define BLK    256
#define PCHUNKS (NFREQ/BLK) // 8 point-chunks per batch elem
#define TRI_CHUNK 32
#define QQ     (MAXN/TRI_CHUNK) // 4 triangle chunks
// workspace: float2 partial[QQ][BB][NFREQ] = 4*64*2048*8 B = 4 MB

// sin(2*pi*x), cos(2*pi*x) via hardware v_sin_f32/v_cos_f32 (input in
// REVOLUTIONS, reduced to [0,1) with v_fract_f32 first).
__device__ __forceinline__ void sincos_2pi(float x, float* s, float* c) {
    float r = __builtin_amdgcn_fractf(x);
    *s = __builtin_amdgcn_sinf(r);
    *c = __builtin_amdgcn_cosf(r);
}

__global__ __launch_bounds__(BLK) void poly_cft_partial(
    const float* __restrict__ tris,    // [64,128,3,2]
    const int*   __restrict__ lengths, // [64]
    float2*      __restrict__ ws)      // [QQ][BB][NFREQ] partial sums
{
    __shared__ float4 sA[TRI_CHUNK];  // xq, yq, e1x=xr-xq, e1y=yr-yq
    __shared__ float4 sB[TRI_CHUNK];  // e2x=xs-xr, e2y=ys-yr, area, unused
    __shared__ float  s_posw[31];

    const int pc = blockIdx.x;                 // 0..7 point chunk
    const int q  = blockIdx.y;                 // 0..3 triangle chunk
    const int b  = blockIdx.z;                 // 0..63 batch elem
    const int p  = (pc << 8) | threadIdx.x;    // 0..2047 freq point
    const int h  = p >> 5;
    const int w  = p & 31;

    const int N   = lengths[b];
    const int n0  = q * TRI_CHUNK;
    const int cnt = min(n0 + TRI_CHUNK, N) - n0;   // may be <= 0

    // Frequency grid values, matching numpy exactly:
    //   g = (1.0/0.1)**(1/30) in double; pos_w[k] = float32(0.1 * g**k)
    if (threadIdx.x < 31) {
        double g = pow(10.0, 1.0 / 30.0);
        s_posw[threadIdx.x] = (float)(0.1 * pow(g, (double)threadIdx.x));
    }

    if ((int)threadIdx.x < cnt) {
        const float* t = tris + ((size_t)b * MAXN + n0 + threadIdx.x) * 6;
        float xq = t[0], yq = t[1];
        float xr = t[2], yr = t[3];
        float xs = t[4], ys = t[5];
        float det  = xq * (yr - ys) + xr * (ys - yq) + xs * (yq - yr);
        float area = fabsf(0.5f * det);
        sA[threadIdx.x] = make_float4(xq, yq, xr - xq, yr - yq);
        sB[threadIdx.x] = make_float4(xs - xr, ys - yr, area, 0.0f);
    }
    __syncthreads();

    // U = Wx[h], V = Wy[w]
    float U;
    if (h < 31)       U = -s_posw[30 - h];
    else if (h == 31) U = 0.0f;
    else if (h < 63)  U = s_posw[h - 32];
    else              U = 0.0f;   // padded row (masked in finalize)
    const float V = (w == 0) ? 0.0f : s_posw[w - 1];

    // float32 constants exactly as the reference builds them:
    const float PI_F     = 3.14159274101257324f;   // np.float32(np.pi)
    const float TWOPI    = 6.28318548202514648f;   // 2*pi_f
    const float FOUR_PI2 = (4.0f * PI_F) * PI_F;   // np.float32(4)*pi*pi

    float accR = 0.0f, accI = 0.0f;

    for (int n = 0; n < cnt; ++n) {
        const float4 A  = sA[n];
        const float4 Bv = sB[n];
        const float xq = A.x,  yq = A.y,  e1x = A.z, e1y = A.w;
        const float e2x = Bv.x, e2y = Bv.y, area = Bv.z;

        // Mask-determining quantities: plain mul/mul/add (no FMA contraction)
        // to reproduce the reference's exact-zero pattern.
        const float U_ = __fadd_rn(__fmul_rn(U, e1x), __fmul_rn(V, e1y));
        const float V_ = __fadd_rn(__fmul_rn(U, e2x), __fmul_rn(V, e2y));
        const float S  = __fadd_rn(U_, V_);

        const bool uz = (U_ == 0.0f);
        const bool vz = (V_ == 0.0f);

        if (uz && vz) {
            accR += area;          // zero_mask: FT = area (real)
        } else {
            float su, cu, sv, cv, sp, cp;
            sincos_2pi(U_, &su, &cu);           // sin/cos(2*pi*U_)
            sincos_2pi(V_, &sv, &cv);           // sin/cos(2*pi*V_)
            const float t = U * xq + V * yq;    // phase arg (not mask-relevant)
            sincos_2pi(t, &sp, &cp);            // sin/cos(2*pi*t)

            float p1, p2r, p2i;
            if (S == 0.0f) {
                p1  = -__builtin_amdgcn_rcpf(FOUR_PI2 * U_ * U_);
                p2r = cu - 1.0f;
                p2i = TWOPI * U_ - su;
            } else if (uz) {
                p1  = -__builtin_amdgcn_rcpf(FOUR_PI2 * V_ * V_);
                p2r = cv - 1.0f;
                p2i = TWOPI * V_ - sv;
            } else if (vz) {
                p1  = __builtin_amdgcn_rcpf(FOUR_PI2 * U_ * U_);
                p2r = cu + TWOPI * U_ * su - 1.0f;
                p2i = TWOPI * U_ * cu - su;
            } else {
                const float cuv = cu * cv - su * sv;   // cos(2pi(U_+V_))
                const float suv = su * cv + cu * sv;   // sin(2pi(U_+V_))
                p1  = __builtin_amdgcn_rcpf(FOUR_PI2 * U_ * V_ * S);
                p2r = -U_ * cuv + S * cu - V_;
                p2i =  U_ * suv - S * su;
            }

            const float k   = 2.0f * area * p1;
            accR += k * (p2r * cp + p2i * sp);
            accI += k * (p2i * cp - p2r * sp);
        }
    }

    ws[((size_t)q * BB + b) * NFREQ + p] = make_float2(accR, accI);
}

__global__ __launch_bounds__(BLK) void poly_cft_finalize(
    const float2* __restrict__ ws,   // [QQ][BB][NFREQ]
    float*        __restrict__ out)  // [2*64*2048]
{
    const int idx = blockIdx.x * BLK + threadIdx.x;  // 0..131071
    const int b = idx >> 11;
    const int p = idx & (NFREQ - 1);
    const int h = p >> 5;

    float accR = 0.0f, accI = 0.0f;
#pragma unroll
    for (int q = 0; q < QQ; ++q) {
        float2 v = ws[((size_t)q * BB + b) * NFREQ + p];
        accR += v.x;
        accI += v.y;
    }

    if (h == 63) { accR = 0.0f; accI = 0.0f; }   // pad row

    const float m2 = __fadd_rn(__fmul_rn(accR, accR), __fmul_rn(accI, accI));
    float mag, ph;
    if (m2 == 0.0f) {
        mag = 0.0f;
        ph  = atan2f(accI, 1.0f);   // angle(0) = 0 semantics
    } else {
        mag = log1pf(sqrtf(m2));
        ph  = atan2f(accI, accR);
    }

    out[idx]              = mag;   // mag block [64,1,64,32]
    out[BB * NFREQ + idx] = ph;    // phase block follows
}

extern "C" void kernel_launch(void* const* d_in, const int* in_sizes, int n_in,
                              void* d_out, int out_size, void* d_ws, size_t ws_size,
                              hipStream_t stream) {
    const float* tris    = (const float*)d_in[0]; // [64,128,3,2] f32
    const int*   lengths = (const int*)d_in[1];   // [64] i32
    float*       out     = (float*)d_out;         // [2*64*2048] f32
    float2*      partial = (float2*)d_ws;         // 4 MB of scratch

    poly_cft_partial<<<dim3(PCHUNKS, QQ, BB), dim3(BLK), 0, stream>>>(tris, lengths, partial);
    poly_cft_finalize<<<dim3(BB * NFREQ / BLK), dim3(BLK), 0, stream>>>(partial, out);
}

// Round 4
// 82.641 us; speedup vs baseline: 1.4617x; 1.0113x over previous
//
#include <hip/hip_runtime.h>
#include <cmath>

// Problem constants (fixed by the reference's init kwargs):
//   POS_FREQS=31, W_MIN=0.1, W_MAX=1.0, PATCH=16 -> grid H=64 (row 63 padded), W=32
//   batch_triangles: [64,128,3,2] f32, lengths: [64] i32
//   outputs: mag [64,1,64,32] f32 then phase [64,1,64,32] f32, concatenated flat.
#define BB     64
#define MAXN   128
#define HH     64
#define WW     32
#define NFREQ  (HH*WW)      // 2048
#define BLK    256
#define PCHUNKS (NFREQ/BLK) // 8 point-chunks per batch elem
#define TRI_CHUNK 16
#define QQ     (MAXN/TRI_CHUNK) // 8 triangle chunks
// workspace: float2 partial[QQ][BB][NFREQ] = 8*64*2048*8 B = 8 MB

// sin(2*pi*x), cos(2*pi*x) via hardware v_sin_f32/v_cos_f32 (input in
// REVOLUTIONS, reduced to [0,1) with v_fract_f32 first).
__device__ __forceinline__ void sincos_2pi(float x, float* s, float* c) {
    float r = __builtin_amdgcn_fractf(x);
    *s = __builtin_amdgcn_sinf(r);
    *c = __builtin_amdgcn_cosf(r);
}

__global__ __launch_bounds__(BLK) void poly_cft_partial(
    const float* __restrict__ tris,    // [64,128,3,2]
    const int*   __restrict__ lengths, // [64]
    float2*      __restrict__ ws)      // [QQ][BB][NFREQ] partial sums
{
    __shared__ float4 sA[TRI_CHUNK];  // xq, yq, e1x=xr-xq, e1y=yr-yq
    __shared__ float4 sB[TRI_CHUNK];  // e2x=xs-xr, e2y=ys-yr, area, unused
    __shared__ float  s_posw[31];

    const int pc = blockIdx.x;                 // 0..7 point chunk
    const int q  = blockIdx.y;                 // 0..7 triangle chunk
    const int b  = blockIdx.z;                 // 0..63 batch elem
    const int p  = (pc << 8) | threadIdx.x;    // 0..2047 freq point
    const int h  = p >> 5;
    const int w  = p & 31;

    const int N   = lengths[b];
    const int n0  = q * TRI_CHUNK;
    const int cnt = min(n0 + TRI_CHUNK, N) - n0;   // may be <= 0

    const size_t wsidx = ((size_t)q * BB + b) * NFREQ + p;

    // Entire chunk out of range: write zeros, exit (block-uniform branch).
    if (cnt <= 0) {
        ws[wsidx] = make_float2(0.0f, 0.0f);
        return;
    }

    // Frequency grid values, matching numpy exactly:
    //   g = (1.0/0.1)**(1/30) in double; pos_w[k] = float32(0.1 * g**k)
    if (threadIdx.x < 31) {
        double g = pow(10.0, 1.0 / 30.0);
        s_posw[threadIdx.x] = (float)(0.1 * pow(g, (double)threadIdx.x));
    }

    // Stage TRI_CHUNK triangles; pad invalid slots with degenerate zeros
    // (U_=V_=0 -> zero-mask branch -> contributes exactly area=0).
    if (threadIdx.x < TRI_CHUNK) {
        if ((int)threadIdx.x < cnt) {
            const float* t = tris + ((size_t)b * MAXN + n0 + threadIdx.x) * 6;
            float xq = t[0], yq = t[1];
            float xr = t[2], yr = t[3];
            float xs = t[4], ys = t[5];
            float det  = xq * (yr - ys) + xr * (ys - yq) + xs * (yq - yr);
            float area = fabsf(0.5f * det);
            sA[threadIdx.x] = make_float4(xq, yq, xr - xq, yr - yq);
            sB[threadIdx.x] = make_float4(xs - xr, ys - yr, area, 0.0f);
        } else {
            sA[threadIdx.x] = make_float4(0.0f, 0.0f, 0.0f, 0.0f);
            sB[threadIdx.x] = make_float4(0.0f, 0.0f, 0.0f, 0.0f);
        }
    }
    __syncthreads();

    // U = Wx[h], V = Wy[w]
    float U;
    if (h < 31)       U = -s_posw[30 - h];
    else if (h == 31) U = 0.0f;
    else if (h < 63)  U = s_posw[h - 32];
    else              U = 0.0f;   // padded row (masked in finalize)
    const float V = (w == 0) ? 0.0f : s_posw[w - 1];

    // float32 constants exactly as the reference builds them:
    const float PI_F     = 3.14159274101257324f;   // np.float32(np.pi)
    const float TWOPI    = 6.28318548202514648f;   // 2*pi_f
    const float FOUR_PI2 = (4.0f * PI_F) * PI_F;   // np.float32(4)*pi*pi

    float accR = 0.0f, accI = 0.0f;

    // Fixed trip count: uniform block cost (load balance) + unroll for ILP
    // so LDS reads batch up and pipeline instead of serializing per iter.
#pragma unroll 4
    for (int n = 0; n < TRI_CHUNK; ++n) {
        const float4 A  = sA[n];
        const float4 Bv = sB[n];
        const float xq = A.x,  yq = A.y,  e1x = A.z, e1y = A.w;
        const float e2x = Bv.x, e2y = Bv.y, area = Bv.z;

        // Mask-determining quantities: plain mul/mul/add (no FMA contraction)
        // to reproduce the reference's exact-zero pattern.
        const float U_ = __fadd_rn(__fmul_rn(U, e1x), __fmul_rn(V, e1y));
        const float V_ = __fadd_rn(__fmul_rn(U, e2x), __fmul_rn(V, e2y));
        const float S  = __fadd_rn(U_, V_);

        const bool uz = (U_ == 0.0f);
        const bool vz = (V_ == 0.0f);

        if (uz && vz) {
            accR += area;          // zero_mask: FT = area (real); padding adds 0
        } else {
            float su, cu, sv, cv, sp, cp;
            sincos_2pi(U_, &su, &cu);           // sin/cos(2*pi*U_)
            sincos_2pi(V_, &sv, &cv);           // sin/cos(2*pi*V_)
            const float t = U * xq + V * yq;    // phase arg (not mask-relevant)
            sincos_2pi(t, &sp, &cp);            // sin/cos(2*pi*t)

            float p1, p2r, p2i;
            if (S == 0.0f) {
                p1  = -__builtin_amdgcn_rcpf(FOUR_PI2 * U_ * U_);
                p2r = cu - 1.0f;
                p2i = TWOPI * U_ - su;
            } else if (uz) {
                p1  = -__builtin_amdgcn_rcpf(FOUR_PI2 * V_ * V_);
                p2r = cv - 1.0f;
                p2i = TWOPI * V_ - sv;
            } else if (vz) {
                p1  = __builtin_amdgcn_rcpf(FOUR_PI2 * U_ * U_);
                p2r = cu + TWOPI * U_ * su - 1.0f;
                p2i = TWOPI * U_ * cu - su;
            } else {
                const float cuv = cu * cv - su * sv;   // cos(2pi(U_+V_))
                const float suv = su * cv + cu * sv;   // sin(2pi(U_+V_))
                p1  = __builtin_amdgcn_rcpf(FOUR_PI2 * U_ * V_ * S);
                p2r = -U_ * cuv + S * cu - V_;
                p2i =  U_ * suv - S * su;
            }

            const float k   = 2.0f * area * p1;
            accR += k * (p2r * cp + p2i * sp);
            accI += k * (p2i * cp - p2r * sp);
        }
    }

    ws[wsidx] = make_float2(accR, accI);
}

__global__ __launch_bounds__(BLK) void poly_cft_finalize(
    const float2* __restrict__ ws,   // [QQ][BB][NFREQ]
    float*        __restrict__ out)  // [2*64*2048]
{
    const int idx = blockIdx.x * BLK + threadIdx.x;  // 0..131071
    const int b = idx >> 11;
    const int p = idx & (NFREQ - 1);
    const int h = p >> 5;

    float accR = 0.0f, accI = 0.0f;
#pragma unroll
    for (int q = 0; q < QQ; ++q) {
        float2 v = ws[((size_t)q * BB + b) * NFREQ + p];
        accR += v.x;
        accI += v.y;
    }

    if (h == 63) { accR = 0.0f; accI = 0.0f; }   // pad row

    const float m2 = __fadd_rn(__fmul_rn(accR, accR), __fmul_rn(accI, accI));
    float mag, ph;
    if (m2 == 0.0f) {
        mag = 0.0f;
        ph  = atan2f(accI, 1.0f);   // angle(0) = 0 semantics
    } else {
        mag = log1pf(sqrtf(m2));
        ph  = atan2f(accI, accR);
    }

    out[idx]              = mag;   // mag block [64,1,64,32]
    out[BB * NFREQ + idx] = ph;    // phase block follows
}

extern "C" void kernel_launch(void* const* d_in, const int* in_sizes, int n_in,
                              void* d_out, int out_size, void* d_ws, size_t ws_size,
                              hipStream_t stream) {
    const float* tris    = (const float*)d_in[0]; // [64,128,3,2] f32
    const int*   lengths = (const int*)d_in[1];   // [64] i32
    float*       out     = (float*)d_out;         // [2*64*2048] f32
    float2*      partial = (float2*)d_ws;         // 8 MB of scratch

    poly_cft_partial<<<dim3(PCHUNKS, QQ, BB), dim3(BLK), 0, stream>>>(tris, lengths, partial);
    poly_cft_finalize<<<dim3(BB * NFREQ / BLK), dim3(BLK), 0, stream>>>(partial, out);
}